// Round 5
// baseline (128.018 us; speedup 1.0000x reference)
//
#include <hip/hip_runtime.h>
#include <stdint.h>

typedef __attribute__((ext_vector_type(4))) float f32x4;
typedef __attribute__((ext_vector_type(8))) short bf16x8;
typedef __attribute__((ext_vector_type(4))) short bf16x4;

#define MFMA16(a, b, c) __builtin_amdgcn_mfma_f32_16x16x32_bf16((a), (b), (c), 0, 0, 0)

__device__ __forceinline__ short f2bf(float f) {
    union { float f; uint32_t u; } v; v.f = f;
    uint32_t r = (v.u + 0x7fffu + ((v.u >> 16) & 1u)) >> 16;
    return (short)(uint16_t)r;
}

__device__ __forceinline__ void async_ld16(const short* g, short* l) {
    __builtin_amdgcn_global_load_lds(
        (const __attribute__((address_space(1))) uint32_t*)g,
        (__attribute__((address_space(3))) uint32_t*)l, 16, 0, 0);
}

// ---------------------------------------------------------------------------
// convert_x: X fp32 [4096*1024] -> bf16 (elementwise, 8/thread)
// ---------------------------------------------------------------------------
__global__ __launch_bounds__(256)
void convert_x(const float* __restrict__ X, short* __restrict__ Xb) {
    const int i8 = (blockIdx.x * 256 + threadIdx.x) << 3;
    f32x4 a = *(const f32x4*)(X + i8);
    f32x4 b = *(const f32x4*)(X + i8 + 4);
    bf16x8 o;
#pragma unroll
    for (int j = 0; j < 4; ++j) { o[j] = f2bf(a[j]); o[4 + j] = f2bf(b[j]); }
    *(bf16x8*)(Xb + i8) = o;
}

// ---------------------------------------------------------------------------
// convert_wt: W fp32 [1024][3072] -> Wt bf16 [3072][1024] (64x64 LDS transpose)
// ---------------------------------------------------------------------------
__global__ __launch_bounds__(256)
void convert_wt(const float* __restrict__ W, short* __restrict__ Wt) {
    __shared__ short T[64][72];
    const int t = threadIdx.x;
    const int n0 = blockIdx.x * 64, k0 = blockIdx.y * 64;
#pragma unroll
    for (int i = 0; i < 4; ++i) {
        const int r = i * 16 + (t >> 4);   // k
        const int c = (t & 15) << 2;       // n
        f32x4 v = *(const f32x4*)(W + (size_t)(k0 + r) * 3072 + n0 + c);
#pragma unroll
        for (int j = 0; j < 4; ++j) T[c + j][r] = f2bf(v[j]);
    }
    __syncthreads();
#pragma unroll
    for (int i = 0; i < 2; ++i) {
        const int r = i * 32 + (t >> 3);   // n
        const int c = (t & 7) << 3;        // k
        *(bf16x8*)(Wt + (size_t)(n0 + r) * 1024 + k0 + c) = *(const bf16x8*)&T[r][c];
    }
}

// ---------------------------------------------------------------------------
// gemm_bf16 (m97 structure): QKV = Xb[4096x1024] @ Wt^T[3072x1024] + bias
// ---------------------------------------------------------------------------
__global__ __launch_bounds__(256, 2)
void gemm_bf16(const short* __restrict__ Xb, const short* __restrict__ Wt,
               const float* __restrict__ bias, short* __restrict__ QKV) {
    __shared__ short Asm[2][128 * 32];
    __shared__ short Bsm[2][128 * 32];

    const int tid  = threadIdx.x;
    const int lane = tid & 63;
    const int l15  = lane & 15;
    const int lq   = lane >> 4;
    const int wave = tid >> 6;
    const int wr = wave >> 1, wc = wave & 1;

    const int bid = blockIdx.x;                    // 768 blocks, 768%8==0
    const int swz = (bid & 7) * 96 + (bid >> 3);
    const int m0 = (swz / 24) * 128, n0 = (swz % 24) * 128;

    const int srow = tid >> 2;
    const int scol = (tid & 3) << 3;

    f32x4 acc[4][4];
#pragma unroll
    for (int m = 0; m < 4; ++m)
#pragma unroll
        for (int n = 0; n < 4; ++n) acc[m][n] = (f32x4)(0.0f);

    auto stage = [&](int k0, int bb) {
#pragma unroll
        for (int i = 0; i < 2; ++i)
            async_ld16(Xb + (size_t)(m0 + i * 64 + srow) * 1024 + k0 + scol,
                       &Asm[bb][(i * 256 + wave * 64) * 8]);
#pragma unroll
        for (int i = 0; i < 2; ++i)
            async_ld16(Wt + (size_t)(n0 + i * 64 + srow) * 1024 + k0 + scol,
                       &Bsm[bb][(i * 256 + wave * 64) * 8]);
    };

    auto compute = [&](int bb) {
        bf16x8 af[4], bfv[4];
#pragma unroll
        for (int m = 0; m < 4; ++m)
            af[m] = *(const bf16x8*)&Asm[bb][(wr * 64 + m * 16 + l15) * 32 + (lq << 3)];
#pragma unroll
        for (int n = 0; n < 4; ++n)
            bfv[n] = *(const bf16x8*)&Bsm[bb][(wc * 64 + n * 16 + l15) * 32 + (lq << 3)];
#pragma unroll
        for (int m = 0; m < 4; ++m)
#pragma unroll
            for (int n = 0; n < 4; ++n) acc[m][n] = MFMA16(af[m], bfv[n], acc[m][n]);
    };

    stage(0, 0);
    __syncthreads();
    int cur = 0;
#pragma unroll 1
    for (int kt = 0; kt < 32; ++kt) {
        if (kt + 1 < 32) stage((kt + 1) * 32, cur ^ 1);
        compute(cur);
        __syncthreads();
        cur ^= 1;
    }

    float bv[4];
#pragma unroll
    for (int n = 0; n < 4; ++n) bv[n] = bias[n0 + wc * 64 + n * 16 + l15];
#pragma unroll
    for (int m = 0; m < 4; ++m) {
        const int row = m0 + wr * 64 + m * 16 + (lq << 2);
#pragma unroll
        for (int n = 0; n < 4; ++n) {
            const int col = n0 + wc * 64 + n * 16 + l15;
#pragma unroll
            for (int r = 0; r < 4; ++r)
                QKV[(size_t)(row + r) * 3072 + col] = f2bf(acc[m][n][r] + bv[n]);
        }
    }
}

// ---------------------------------------------------------------------------
// Causal flash attention v4: grid (32,32) longest-first (qt = 31-bx),
// 4 blocks/CU resident; peeled diagonal tile; T13 defer-rescale;
// paired-dword V-transpose writes. Swapped QK^T + in-register softmax +
// cvt_pk/bpermute P redistribution (from v3). Out fp32 [B,H,S,d].
// ---------------------------------------------------------------------------
#define DPAD 72

__global__ __launch_bounds__(256, 4)
void attn_fwd(const short* __restrict__ QKV, float* __restrict__ Out) {
    __shared__ short Ksm[2][64 * DPAD];   // K[kv][d]
    __shared__ short Vsm[2][64 * DPAD];   // V^T[d][kv]

    const int tid  = threadIdx.x;
    const int lane = tid & 63;
    const int l15  = lane & 15;
    const int lq   = lane >> 4;
    const int wave = tid >> 6;
    const int bh = blockIdx.y;
    const int b = bh >> 4, h = bh & 15;

    const short* base = QKV + (size_t)b * 2048 * 3072 + h * 192;

    // K staging: 2x b128 per thread
    const int kr = tid >> 3, kc = (tid & 7) << 3;
    // V staging: thread owns kv pair (2*r2, 2*r2+1) x 8 d's -> 8 packed dwords
    const int r2 = tid & 31;               // kv pair index
    const int d0 = (tid >> 5) << 3;        // d base (0..56 step 8)

    const float SCALE2 = 0.03125f * 1.44269504f;  // 1/sqrt(1024) * log2(e)

    // bpermute byte-addresses for P redistribution (lane-constant)
    const int addrA = ((((2 * lq) & 3) << 4) + l15) << 2;
    const int addrB = ((((2 * lq + 1) & 3) << 4) + l15) << 2;
    const bool hi2 = (lq >> 1) != 0;

    const int qt = 31 - (int)blockIdx.x;   // longest blocks dispatch first
    const int q0 = qt * 64;

    bf16x8 kreg[2], vreg[2];

    auto load_tile_regs = [&](int kv0) {
#pragma unroll
        for (int p = 0; p < 2; ++p)
            kreg[p] = *(const bf16x8*)(base + (size_t)(kv0 + kr + p * 32) * 3072 + 64 + kc);
#pragma unroll
        for (int p = 0; p < 2; ++p)
            vreg[p] = *(const bf16x8*)(base + (size_t)(kv0 + 2 * r2 + p) * 3072 + 128 + d0);
    };

    auto write_tile_lds = [&](int bb) {
#pragma unroll
        for (int p = 0; p < 2; ++p)
            *(bf16x8*)&Ksm[bb][(kr + p * 32) * DPAD + kc] = kreg[p];
#pragma unroll
        for (int j = 0; j < 8; ++j) {
            union { uint16_t s[2]; uint32_t u; } w;
            w.s[0] = (uint16_t)vreg[0][j];
            w.s[1] = (uint16_t)vreg[1][j];
            *(uint32_t*)&Vsm[bb][(d0 + j) * DPAD + 2 * r2] = w.u;
        }
    };

    bf16x8 qf[2];
    {
        const short* qp = base + (size_t)(q0 + wave * 16 + l15) * 3072 + (lq << 3);
        qf[0] = *(const bf16x8*)qp;
        qf[1] = *(const bf16x8*)(qp + 32);
    }

    f32x4 o[4];
#pragma unroll
    for (int n = 0; n < 4; ++n) o[n] = (f32x4)(0.0f);
    float m_run = -1e30f, l_run = 0.f;

    const int qg = q0 + wave * 16 + l15;

    // tile body; DIAG constant-folds at both call sites
    auto tile_body = [&](int bb, int kv0, bool DIAG) {
        // swapped QK^T: lane holds q=l15, kv = n*16 + lq*4 + r
        float p[4][4];
#pragma unroll
        for (int n = 0; n < 4; ++n) {
            const short* kp = &Ksm[bb][(n * 16 + l15) * DPAD + (lq << 3)];
            bf16x8 k0 = *(const bf16x8*)kp;
            bf16x8 k1 = *(const bf16x8*)(kp + 32);
            f32x4 z = (f32x4)(0.0f);
            z = MFMA16(k0, qf[0], z);
            z = MFMA16(k1, qf[1], z);
#pragma unroll
            for (int r = 0; r < 4; ++r) p[n][r] = z[r];
        }

#pragma unroll
        for (int n = 0; n < 4; ++n)
#pragma unroll
            for (int r = 0; r < 4; ++r) {
                float x = p[n][r] * SCALE2;
                if (DIAG && (kv0 + n * 16 + (lq << 2) + r) > qg) x = -1e30f;
                p[n][r] = x;
            }

        // row max (tree -> 2 shfl)
        float m01 = fmaxf(fmaxf(p[0][0], p[0][1]), fmaxf(p[0][2], p[0][3]));
        float m23 = fmaxf(fmaxf(p[1][0], p[1][1]), fmaxf(p[1][2], p[1][3]));
        float m45 = fmaxf(fmaxf(p[2][0], p[2][1]), fmaxf(p[2][2], p[2][3]));
        float m67 = fmaxf(fmaxf(p[3][0], p[3][1]), fmaxf(p[3][2], p[3][3]));
        float mx = fmaxf(fmaxf(m01, m23), fmaxf(m45, m67));
        mx = fmaxf(mx, __shfl_xor(mx, 16, 64));
        mx = fmaxf(mx, __shfl_xor(mx, 32, 64));

        // T13 defer-rescale: only rescale when max grew by > 8 (exp2 units)
        if (!__all(mx <= m_run + 8.f)) {
            const float mnew = fmaxf(m_run, mx);
            const float corr = exp2f(m_run - mnew);
            l_run *= corr;
#pragma unroll
            for (int n = 0; n < 4; ++n) o[n] *= corr;
            m_run = mnew;
        }

        float ps = 0.f;
#pragma unroll
        for (int n = 0; n < 4; ++n)
#pragma unroll
            for (int r = 0; r < 4; ++r) {
                p[n][r] = exp2f(p[n][r] - m_run);
                ps += p[n][r];
            }
        ps += __shfl_xor(ps, 16, 64);
        ps += __shfl_xor(ps, 32, 64);
        l_run += ps;

        // pack P -> bf16 dwords
        uint32_t wv[4][2];
#pragma unroll
        for (int n = 0; n < 4; ++n)
#pragma unroll
            for (int v = 0; v < 2; ++v)
                asm("v_cvt_pk_bf16_f32 %0, %1, %2"
                    : "=v"(wv[n][v]) : "v"(p[n][2 * v]), "v"(p[n][2 * v + 1]));

        // redistribute to x32 B-frag layout
        uint32_t W0[4], W1[4];
#pragma unroll
        for (int jw = 0; jw < 4; ++jw) {
            const int addr = (jw < 2) ? addrA : addrB;
            const int u = jw & 1;
            int f0 = __builtin_amdgcn_ds_bpermute(addr, (int)wv[0][u]);
            int f1 = __builtin_amdgcn_ds_bpermute(addr, (int)wv[1][u]);
            W0[jw] = hi2 ? (uint32_t)f1 : (uint32_t)f0;
            int g0 = __builtin_amdgcn_ds_bpermute(addr, (int)wv[2][u]);
            int g1 = __builtin_amdgcn_ds_bpermute(addr, (int)wv[3][u]);
            W1[jw] = hi2 ? (uint32_t)g1 : (uint32_t)g0;
        }
        union { uint32_t u[4]; bf16x8 v; } pb0, pb1;
#pragma unroll
        for (int i = 0; i < 4; ++i) { pb0.u[i] = W0[i]; pb1.u[i] = W1[i]; }

        // PV: O^T[d][q] += V^T . P^T
#pragma unroll
        for (int n = 0; n < 4; ++n) {
            const short* vp = &Vsm[bb][(n * 16 + l15) * DPAD + (lq << 3)];
            bf16x8 v0 = *(const bf16x8*)vp;
            bf16x8 v1 = *(const bf16x8*)(vp + 32);
            o[n] = MFMA16(v0, pb0.v, o[n]);
            o[n] = MFMA16(v1, pb1.v, o[n]);
        }
    };

    // prologue: stage tile 0
    load_tile_regs(0);
    write_tile_lds(0);
    __syncthreads();
    int cur = 0;

    // main loop: non-diagonal tiles (no mask VALU)
#pragma unroll 1
    for (int t = 0; t < qt; ++t) {
        load_tile_regs((t + 1) * 64);
        tile_body(cur, t * 64, false);
        write_tile_lds(cur ^ 1);
        __syncthreads();
        cur ^= 1;
    }
    // peeled diagonal tile
    tile_body(cur, qt * 64, true);

    // epilogue: lane owns q-row q0+wave*16+l15, d = n*16 + lq*4..+3
    const float inv = 1.f / l_run;
    const size_t orow = ((size_t)(b * 16 + h) * 2048 + (q0 + wave * 16 + l15)) * 64;
#pragma unroll
    for (int n = 0; n < 4; ++n) {
        f32x4 ov = o[n] * inv;
        *(f32x4*)(Out + orow + n * 16 + (lq << 2)) = ov;
    }
}

extern "C" void kernel_launch(void* const* d_in, const int* in_sizes, int n_in,
                              void* d_out, int out_size, void* d_ws, size_t ws_size,
                              hipStream_t stream) {
    const float* x  = (const float*)d_in[0];
    const float* W0 = (const float*)d_in[1];
    const float* b0 = (const float*)d_in[2];
    float* out = (float*)d_out;
    char* ws = (char*)d_ws;

    const size_t QKV_B = (size_t)4096 * 3072 * 2;  // 25.2 MB
    const size_t XBF_B = (size_t)4096 * 1024 * 2;  // 8.4 MB

    short* qkv = (short*)ws;
    short* xb  = (short*)(ws + QKV_B);
    short* wt  = (short*)(ws + QKV_B + XBF_B);

    convert_x<<<dim3(2048), dim3(256), 0, stream>>>(x, xb);
    convert_wt<<<dim3(48, 16), dim3(256), 0, stream>>>(W0, wt);
    gemm_bf16<<<dim3(768), dim3(256), 0, stream>>>(xb, wt, b0, qkv);
    attn_fwd<<<dim3(32, 32), dim3(256), 0, stream>>>(qkv, out);
}

// Round 6
// 116.308 us; speedup vs baseline: 1.1007x; 1.1007x over previous
//
#include <hip/hip_runtime.h>
#include <stdint.h>

typedef __attribute__((ext_vector_type(4))) float f32x4;
typedef __attribute__((ext_vector_type(8))) short bf16x8;
typedef __attribute__((ext_vector_type(4))) short bf16x4;

#define MFMA16(a, b, c) __builtin_amdgcn_mfma_f32_16x16x32_bf16((a), (b), (c), 0, 0, 0)

__device__ __forceinline__ short f2bf(float f) {
    union { float f; uint32_t u; } v; v.f = f;
    uint32_t r = (v.u + 0x7fffu + ((v.u >> 16) & 1u)) >> 16;
    return (short)(uint16_t)r;
}
__device__ __forceinline__ float bf2f(short s) {
    union { uint32_t u; float f; } v; v.u = ((uint32_t)(uint16_t)s) << 16;
    return v.f;
}

__device__ __forceinline__ void async_ld16(const short* g, short* l) {
    __builtin_amdgcn_global_load_lds(
        (const __attribute__((address_space(1))) uint32_t*)g,
        (__attribute__((address_space(3))) uint32_t*)l, 16, 0, 0);
}

// ---------------------------------------------------------------------------
// convert_x: X fp32 [4096*1024] -> bf16
// ---------------------------------------------------------------------------
__global__ __launch_bounds__(256)
void convert_x(const float* __restrict__ X, short* __restrict__ Xb) {
    const int i8 = (blockIdx.x * 256 + threadIdx.x) << 3;
    f32x4 a = *(const f32x4*)(X + i8);
    f32x4 b = *(const f32x4*)(X + i8 + 4);
    bf16x8 o;
#pragma unroll
    for (int j = 0; j < 4; ++j) { o[j] = f2bf(a[j]); o[4 + j] = f2bf(b[j]); }
    *(bf16x8*)(Xb + i8) = o;
}

// ---------------------------------------------------------------------------
// convert_wt: W fp32 [1024][3072] -> Wt bf16 [3072][1024]
// ---------------------------------------------------------------------------
__global__ __launch_bounds__(256)
void convert_wt(const float* __restrict__ W, short* __restrict__ Wt) {
    __shared__ short T[64][72];
    const int t = threadIdx.x;
    const int n0 = blockIdx.x * 64, k0 = blockIdx.y * 64;
#pragma unroll
    for (int i = 0; i < 4; ++i) {
        const int r = i * 16 + (t >> 4);
        const int c = (t & 15) << 2;
        f32x4 v = *(const f32x4*)(W + (size_t)(k0 + r) * 3072 + n0 + c);
#pragma unroll
        for (int j = 0; j < 4; ++j) T[c + j][r] = f2bf(v[j]);
    }
    __syncthreads();
#pragma unroll
    for (int i = 0; i < 2; ++i) {
        const int r = i * 32 + (t >> 3);
        const int c = (t & 7) << 3;
        *(bf16x8*)(Wt + (size_t)(n0 + r) * 1024 + k0 + c) = *(const bf16x8*)&T[r][c];
    }
}

// ---------------------------------------------------------------------------
// gemm_bf16 (m97 structure): QKV = Xb @ Wt^T + bias, output bf16  (unchanged)
// ---------------------------------------------------------------------------
__global__ __launch_bounds__(256, 2)
void gemm_bf16(const short* __restrict__ Xb, const short* __restrict__ Wt,
               const float* __restrict__ bias, short* __restrict__ QKV) {
    __shared__ short Asm[2][128 * 32];
    __shared__ short Bsm[2][128 * 32];

    const int tid  = threadIdx.x;
    const int lane = tid & 63;
    const int l15  = lane & 15;
    const int lq   = lane >> 4;
    const int wave = tid >> 6;
    const int wr = wave >> 1, wc = wave & 1;

    const int bid = blockIdx.x;
    const int swz = (bid & 7) * 96 + (bid >> 3);
    const int m0 = (swz / 24) * 128, n0 = (swz % 24) * 128;

    const int srow = tid >> 2;
    const int scol = (tid & 3) << 3;

    f32x4 acc[4][4];
#pragma unroll
    for (int m = 0; m < 4; ++m)
#pragma unroll
        for (int n = 0; n < 4; ++n) acc[m][n] = (f32x4)(0.0f);

    auto stage = [&](int k0, int bb) {
#pragma unroll
        for (int i = 0; i < 2; ++i)
            async_ld16(Xb + (size_t)(m0 + i * 64 + srow) * 1024 + k0 + scol,
                       &Asm[bb][(i * 256 + wave * 64) * 8]);
#pragma unroll
        for (int i = 0; i < 2; ++i)
            async_ld16(Wt + (size_t)(n0 + i * 64 + srow) * 1024 + k0 + scol,
                       &Bsm[bb][(i * 256 + wave * 64) * 8]);
    };

    auto compute = [&](int bb) {
        bf16x8 af[4], bfv[4];
#pragma unroll
        for (int m = 0; m < 4; ++m)
            af[m] = *(const bf16x8*)&Asm[bb][(wr * 64 + m * 16 + l15) * 32 + (lq << 3)];
#pragma unroll
        for (int n = 0; n < 4; ++n)
            bfv[n] = *(const bf16x8*)&Bsm[bb][(wc * 64 + n * 16 + l15) * 32 + (lq << 3)];
#pragma unroll
        for (int m = 0; m < 4; ++m)
#pragma unroll
            for (int n = 0; n < 4; ++n) acc[m][n] = MFMA16(af[m], bfv[n], acc[m][n]);
    };

    stage(0, 0);
    __syncthreads();
    int cur = 0;
#pragma unroll 1
    for (int kt = 0; kt < 32; ++kt) {
        if (kt + 1 < 32) stage((kt + 1) * 32, cur ^ 1);
        compute(cur);
        __syncthreads();
        cur ^= 1;
    }

    float bv[4];
#pragma unroll
    for (int n = 0; n < 4; ++n) bv[n] = bias[n0 + wc * 64 + n * 16 + l15];
#pragma unroll
    for (int m = 0; m < 4; ++m) {
        const int row = m0 + wr * 64 + m * 16 + (lq << 2);
#pragma unroll
        for (int n = 0; n < 4; ++n) {
            const int col = n0 + wc * 64 + n * 16 + l15;
#pragma unroll
            for (int r = 0; r < 4; ++r)
                QKV[(size_t)(row + r) * 3072 + col] = f2bf(acc[m][n][r] + bv[n]);
        }
    }
}

// ---------------------------------------------------------------------------
// attn_part: flash-decoding kv-chunked causal attention partials.
// Chunk map (u = blockIdx.x, 0..47):
//   u<16 : qt=u+16, tiles [0,16)      (size 16, no diagonal)
//   u<32 : qt=47-u, tiles [16,qt+1)   (sizes 16..1, diagonal)
//   else : qt=47-u, tiles [0,qt+1)    (sizes 16..1, diagonal)
// Output per q-row: normalized o (bf16[64]) + lse m' = m + log2(l) (fp32).
// ---------------------------------------------------------------------------
#define DPAD 72

__global__ __launch_bounds__(256, 4)
void attn_part(const short* __restrict__ QKV, short* __restrict__ Po,
               float* __restrict__ Pm) {
    __shared__ short Ksm[2][64 * DPAD];   // K[kv][d]
    __shared__ short Vsm[2][64 * DPAD];   // V^T[d][kv]

    const int tid  = threadIdx.x;
    const int lane = tid & 63;
    const int l15  = lane & 15;
    const int lq   = lane >> 4;
    const int wave = tid >> 6;
    const int bh = blockIdx.y;
    const int b = bh >> 4, h = bh & 15;
    const int u = blockIdx.x;

    int qt, t0, t1;
    if (u < 16)      { qt = u + 16; t0 = 0;  t1 = 16; }
    else if (u < 32) { qt = 47 - u; t0 = 16; t1 = qt + 1; }
    else             { qt = 47 - u; t0 = 0;  t1 = qt + 1; }
    const bool hasDiag = (t1 - 1 == qt);
    const int q0 = qt * 64;

    const short* base = QKV + (size_t)b * 2048 * 3072 + h * 192;

    const int kr = tid >> 3, kc = (tid & 7) << 3;
    const int r2 = tid & 31;
    const int d0 = (tid >> 5) << 3;

    const float SCALE2 = 0.03125f * 1.44269504f;

    const int addrA = ((((2 * lq) & 3) << 4) + l15) << 2;
    const int addrB = ((((2 * lq + 1) & 3) << 4) + l15) << 2;
    const bool hi2 = (lq >> 1) != 0;

    bf16x8 kreg[2], vreg[2];

    auto load_tile_regs = [&](int kv0) {
#pragma unroll
        for (int p = 0; p < 2; ++p)
            kreg[p] = *(const bf16x8*)(base + (size_t)(kv0 + kr + p * 32) * 3072 + 64 + kc);
#pragma unroll
        for (int p = 0; p < 2; ++p)
            vreg[p] = *(const bf16x8*)(base + (size_t)(kv0 + 2 * r2 + p) * 3072 + 128 + d0);
    };

    auto write_tile_lds = [&](int bb) {
#pragma unroll
        for (int p = 0; p < 2; ++p)
            *(bf16x8*)&Ksm[bb][(kr + p * 32) * DPAD + kc] = kreg[p];
#pragma unroll
        for (int j = 0; j < 8; ++j) {
            union { uint16_t s[2]; uint32_t u32; } w;
            w.s[0] = (uint16_t)vreg[0][j];
            w.s[1] = (uint16_t)vreg[1][j];
            *(uint32_t*)&Vsm[bb][(d0 + j) * DPAD + 2 * r2] = w.u32;
        }
    };

    bf16x8 qf[2];
    {
        const short* qp = base + (size_t)(q0 + wave * 16 + l15) * 3072 + (lq << 3);
        qf[0] = *(const bf16x8*)qp;
        qf[1] = *(const bf16x8*)(qp + 32);
    }

    f32x4 o[4];
#pragma unroll
    for (int n = 0; n < 4; ++n) o[n] = (f32x4)(0.0f);
    float m_run = -1e30f, l_run = 0.f;

    const int qg = q0 + wave * 16 + l15;

    auto tile_body = [&](int bb, int kv0, bool DIAG) {
        float p[4][4];
#pragma unroll
        for (int n = 0; n < 4; ++n) {
            const short* kp = &Ksm[bb][(n * 16 + l15) * DPAD + (lq << 3)];
            bf16x8 k0 = *(const bf16x8*)kp;
            bf16x8 k1 = *(const bf16x8*)(kp + 32);
            f32x4 z = (f32x4)(0.0f);
            z = MFMA16(k0, qf[0], z);
            z = MFMA16(k1, qf[1], z);
#pragma unroll
            for (int r = 0; r < 4; ++r) p[n][r] = z[r];
        }

#pragma unroll
        for (int n = 0; n < 4; ++n)
#pragma unroll
            for (int r = 0; r < 4; ++r) {
                float x = p[n][r] * SCALE2;
                if (DIAG && (kv0 + n * 16 + (lq << 2) + r) > qg) x = -1e30f;
                p[n][r] = x;
            }

        float m01 = fmaxf(fmaxf(p[0][0], p[0][1]), fmaxf(p[0][2], p[0][3]));
        float m23 = fmaxf(fmaxf(p[1][0], p[1][1]), fmaxf(p[1][2], p[1][3]));
        float m45 = fmaxf(fmaxf(p[2][0], p[2][1]), fmaxf(p[2][2], p[2][3]));
        float m67 = fmaxf(fmaxf(p[3][0], p[3][1]), fmaxf(p[3][2], p[3][3]));
        float mx = fmaxf(fmaxf(m01, m23), fmaxf(m45, m67));
        mx = fmaxf(mx, __shfl_xor(mx, 16, 64));
        mx = fmaxf(mx, __shfl_xor(mx, 32, 64));

        if (!__all(mx <= m_run + 8.f)) {
            const float mnew = fmaxf(m_run, mx);
            const float corr = exp2f(m_run - mnew);
            l_run *= corr;
#pragma unroll
            for (int n = 0; n < 4; ++n) o[n] *= corr;
            m_run = mnew;
        }

        float ps = 0.f;
#pragma unroll
        for (int n = 0; n < 4; ++n)
#pragma unroll
            for (int r = 0; r < 4; ++r) {
                p[n][r] = exp2f(p[n][r] - m_run);
                ps += p[n][r];
            }
        ps += __shfl_xor(ps, 16, 64);
        ps += __shfl_xor(ps, 32, 64);
        l_run += ps;

        uint32_t wv[4][2];
#pragma unroll
        for (int n = 0; n < 4; ++n)
#pragma unroll
            for (int v = 0; v < 2; ++v)
                asm("v_cvt_pk_bf16_f32 %0, %1, %2"
                    : "=v"(wv[n][v]) : "v"(p[n][2 * v]), "v"(p[n][2 * v + 1]));

        uint32_t W0[4], W1[4];
#pragma unroll
        for (int jw = 0; jw < 4; ++jw) {
            const int addr = (jw < 2) ? addrA : addrB;
            const int uu = jw & 1;
            int f0 = __builtin_amdgcn_ds_bpermute(addr, (int)wv[0][uu]);
            int f1 = __builtin_amdgcn_ds_bpermute(addr, (int)wv[1][uu]);
            W0[jw] = hi2 ? (uint32_t)f1 : (uint32_t)f0;
            int g0 = __builtin_amdgcn_ds_bpermute(addr, (int)wv[2][uu]);
            int g1 = __builtin_amdgcn_ds_bpermute(addr, (int)wv[3][uu]);
            W1[jw] = hi2 ? (uint32_t)g1 : (uint32_t)g0;
        }
        union { uint32_t u32[4]; bf16x8 v; } pb0, pb1;
#pragma unroll
        for (int i = 0; i < 4; ++i) { pb0.u32[i] = W0[i]; pb1.u32[i] = W1[i]; }

#pragma unroll
        for (int n = 0; n < 4; ++n) {
            const short* vp = &Vsm[bb][(n * 16 + l15) * DPAD + (lq << 3)];
            bf16x8 v0 = *(const bf16x8*)vp;
            bf16x8 v1 = *(const bf16x8*)(vp + 32);
            o[n] = MFMA16(v0, pb0.v, o[n]);
            o[n] = MFMA16(v1, pb1.v, o[n]);
        }
    };

    // prologue
    load_tile_regs(t0 * 64);
    write_tile_lds(0);
    __syncthreads();
    int cur = 0;

#pragma unroll 1
    for (int t = t0; t < t1 - 1; ++t) {
        load_tile_regs((t + 1) * 64);
        tile_body(cur, t * 64, false);
        write_tile_lds(cur ^ 1);
        __syncthreads();
        cur ^= 1;
    }
    if (hasDiag) tile_body(cur, (t1 - 1) * 64, true);
    else         tile_body(cur, (t1 - 1) * 64, false);

    // epilogue: normalized bf16 partial + fp32 lse
    const float inv = 1.f / l_run;
    const int prow = (bh * 48 + u) * 64 + wave * 16 + l15;
#pragma unroll
    for (int n = 0; n < 4; ++n) {
        bf16x4 w;
#pragma unroll
        for (int j = 0; j < 4; ++j) w[j] = f2bf(o[n][j] * inv);
        *(bf16x4*)&Po[(size_t)prow * 64 + n * 16 + (lq << 2)] = w;
    }
    if (lq == 0) Pm[prow] = m_run + __log2f(l_run);
}

// ---------------------------------------------------------------------------
// attn_combine: merge <=2 partials per q-row -> fp32 Out [B,H,S,64] flat.
// ---------------------------------------------------------------------------
__global__ __launch_bounds__(256)
void attn_combine(const short* __restrict__ Po, const float* __restrict__ Pm,
                  float* __restrict__ Out) {
    const int idx = blockIdx.x * 256 + threadIdx.x;  // 0 .. 1048575
    const int d4 = (idx & 15) << 2;
    const int rg = idx >> 4;          // 0..65535 = bh*2048 + q
    const int q  = rg & 2047;
    const int bh = rg >> 11;
    const int qt = q >> 6, r = q & 63;

    f32x4 ov;
    if (qt < 16) {
        const int p0 = (bh * 48 + (47 - qt)) * 64 + r;
        bf16x4 a = *(const bf16x4*)&Po[(size_t)p0 * 64 + d4];
#pragma unroll
        for (int j = 0; j < 4; ++j) ov[j] = bf2f(a[j]);
    } else {
        const int p0 = (bh * 48 + (qt - 16)) * 64 + r;
        const int p1 = (bh * 48 + (47 - qt)) * 64 + r;
        bf16x4 a = *(const bf16x4*)&Po[(size_t)p0 * 64 + d4];
        bf16x4 c = *(const bf16x4*)&Po[(size_t)p1 * 64 + d4];
        const float m0 = Pm[p0], m1 = Pm[p1];
        const float M = fmaxf(m0, m1);
        const float w0 = exp2f(m0 - M), w1 = exp2f(m1 - M);
        const float inv = 1.f / (w0 + w1);
#pragma unroll
        for (int j = 0; j < 4; ++j) ov[j] = (w0 * bf2f(a[j]) + w1 * bf2f(c[j])) * inv;
    }
    *(f32x4*)&Out[(size_t)rg * 64 + d4] = ov;
}

extern "C" void kernel_launch(void* const* d_in, const int* in_sizes, int n_in,
                              void* d_out, int out_size, void* d_ws, size_t ws_size,
                              hipStream_t stream) {
    const float* x  = (const float*)d_in[0];
    const float* W0 = (const float*)d_in[1];
    const float* b0 = (const float*)d_in[2];
    float* out = (float*)d_out;
    char* ws = (char*)d_ws;

    const size_t QKV_B = (size_t)4096 * 3072 * 2;   // 25.17 MB
    const size_t XBF_B = (size_t)4096 * 1024 * 2;   // 8.39 MB
    const size_t PO_B  = (size_t)1536 * 64 * 64 * 2;  // 12.58 MB

    short* qkv = (short*)ws;
    short* xb  = (short*)(ws + QKV_B);
    short* wt  = (short*)(ws + QKV_B + XBF_B);
    // partials reuse xb/wt region (dead after gemm); peak ws stays ~40 MB
    short* po  = (short*)(ws + QKV_B);
    float* pm  = (float*)(ws + QKV_B + PO_B);

    convert_x<<<dim3(2048), dim3(256), 0, stream>>>(x, xb);
    convert_wt<<<dim3(48, 16), dim3(256), 0, stream>>>(W0, wt);
    gemm_bf16<<<dim3(768), dim3(256), 0, stream>>>(xb, wt, b0, qkv);
    attn_part<<<dim3(48, 32), dim3(256), 0, stream>>>(qkv, po, pm);
    attn_combine<<<dim3(4096), dim3(256), 0, stream>>>(po, pm, out);
}

// Round 8
// 115.551 us; speedup vs baseline: 1.1079x; 1.0065x over previous
//
#include <hip/hip_runtime.h>
#include <stdint.h>

typedef __attribute__((ext_vector_type(4))) float f32x4;
typedef __attribute__((ext_vector_type(8))) short bf16x8;
typedef __attribute__((ext_vector_type(4))) short bf16x4;

#define MFMA16(a, b, c) __builtin_amdgcn_mfma_f32_16x16x32_bf16((a), (b), (c), 0, 0, 0)

__device__ __forceinline__ short f2bf(float f) {
    union { float f; uint32_t u; } v; v.f = f;
    uint32_t r = (v.u + 0x7fffu + ((v.u >> 16) & 1u)) >> 16;
    return (short)(uint16_t)r;
}
__device__ __forceinline__ float bf2f(short s) {
    union { uint32_t u; float f; } v; v.u = ((uint32_t)(uint16_t)s) << 16;
    return v.f;
}

__device__ __forceinline__ void async_ld16(const short* g, short* l) {
    __builtin_amdgcn_global_load_lds(
        (const __attribute__((address_space(1))) uint32_t*)g,
        (__attribute__((address_space(3))) uint32_t*)l, 16, 0, 0);
}

// ---------------------------------------------------------------------------
// convert_x: X fp32 [4096*1024] -> bf16
// ---------------------------------------------------------------------------
__global__ __launch_bounds__(256)
void convert_x(const float* __restrict__ X, short* __restrict__ Xb) {
    const int i8 = (blockIdx.x * 256 + threadIdx.x) << 3;
    f32x4 a = *(const f32x4*)(X + i8);
    f32x4 b = *(const f32x4*)(X + i8 + 4);
    bf16x8 o;
#pragma unroll
    for (int j = 0; j < 4; ++j) { o[j] = f2bf(a[j]); o[4 + j] = f2bf(b[j]); }
    *(bf16x8*)(Xb + i8) = o;
}

// ---------------------------------------------------------------------------
// convert_wt: W fp32 [1024][3072] -> Wt bf16 [3072][1024]
// ---------------------------------------------------------------------------
__global__ __launch_bounds__(256)
void convert_wt(const float* __restrict__ W, short* __restrict__ Wt) {
    __shared__ short T[64][72];
    const int t = threadIdx.x;
    const int n0 = blockIdx.x * 64, k0 = blockIdx.y * 64;
#pragma unroll
    for (int i = 0; i < 4; ++i) {
        const int r = i * 16 + (t >> 4);
        const int c = (t & 15) << 2;
        f32x4 v = *(const f32x4*)(W + (size_t)(k0 + r) * 3072 + n0 + c);
#pragma unroll
        for (int j = 0; j < 4; ++j) T[c + j][r] = f2bf(v[j]);
    }
    __syncthreads();
#pragma unroll
    for (int i = 0; i < 2; ++i) {
        const int r = i * 32 + (t >> 3);
        const int c = (t & 7) << 3;
        *(bf16x8*)(Wt + (size_t)(n0 + r) * 1024 + k0 + c) = *(const bf16x8*)&T[r][c];
    }
}

// ---------------------------------------------------------------------------
// gemm_bf16 (m97 structure): QKV = Xb @ Wt^T + bias, output bf16  (unchanged)
// ---------------------------------------------------------------------------
__global__ __launch_bounds__(256, 2)
void gemm_bf16(const short* __restrict__ Xb, const short* __restrict__ Wt,
               const float* __restrict__ bias, short* __restrict__ QKV) {
    __shared__ short Asm[2][128 * 32];
    __shared__ short Bsm[2][128 * 32];

    const int tid  = threadIdx.x;
    const int lane = tid & 63;
    const int l15  = lane & 15;
    const int lq   = lane >> 4;
    const int wave = tid >> 6;
    const int wr = wave >> 1, wc = wave & 1;

    const int bid = blockIdx.x;
    const int swz = (bid & 7) * 96 + (bid >> 3);
    const int m0 = (swz / 24) * 128, n0 = (swz % 24) * 128;

    const int srow = tid >> 2;
    const int scol = (tid & 3) << 3;

    f32x4 acc[4][4];
#pragma unroll
    for (int m = 0; m < 4; ++m)
#pragma unroll
        for (int n = 0; n < 4; ++n) acc[m][n] = (f32x4)(0.0f);

    auto stage = [&](int k0, int bb) {
#pragma unroll
        for (int i = 0; i < 2; ++i)
            async_ld16(Xb + (size_t)(m0 + i * 64 + srow) * 1024 + k0 + scol,
                       &Asm[bb][(i * 256 + wave * 64) * 8]);
#pragma unroll
        for (int i = 0; i < 2; ++i)
            async_ld16(Wt + (size_t)(n0 + i * 64 + srow) * 1024 + k0 + scol,
                       &Bsm[bb][(i * 256 + wave * 64) * 8]);
    };

    auto compute = [&](int bb) {
        bf16x8 af[4], bfv[4];
#pragma unroll
        for (int m = 0; m < 4; ++m)
            af[m] = *(const bf16x8*)&Asm[bb][(wr * 64 + m * 16 + l15) * 32 + (lq << 3)];
#pragma unroll
        for (int n = 0; n < 4; ++n)
            bfv[n] = *(const bf16x8*)&Bsm[bb][(wc * 64 + n * 16 + l15) * 32 + (lq << 3)];
#pragma unroll
        for (int m = 0; m < 4; ++m)
#pragma unroll
            for (int n = 0; n < 4; ++n) acc[m][n] = MFMA16(af[m], bfv[n], acc[m][n]);
    };

    stage(0, 0);
    __syncthreads();
    int cur = 0;
#pragma unroll 1
    for (int kt = 0; kt < 32; ++kt) {
        if (kt + 1 < 32) stage((kt + 1) * 32, cur ^ 1);
        compute(cur);
        __syncthreads();
        cur ^= 1;
    }

    float bv[4];
#pragma unroll
    for (int n = 0; n < 4; ++n) bv[n] = bias[n0 + wc * 64 + n * 16 + l15];
#pragma unroll
    for (int m = 0; m < 4; ++m) {
        const int row = m0 + wr * 64 + m * 16 + (lq << 2);
#pragma unroll
        for (int n = 0; n < 4; ++n) {
            const int col = n0 + wc * 64 + n * 16 + l15;
#pragma unroll
            for (int r = 0; r < 4; ++r)
                QKV[(size_t)(row + r) * 3072 + col] = f2bf(acc[m][n][r] + bv[n]);
        }
    }
}

// ---------------------------------------------------------------------------
// attn_part v5b: K via global_load_lds (dbuf, both-sides XOR swizzle — fixed
// k1 read: position is (lq+4)^(row&7), NOT (lq^(row&7))+4), single-buffer
// V^T (reg-staged), LDS 25.6KB -> 6 blocks/CU, pre-scaled Q, ptr-increment.
// ---------------------------------------------------------------------------
#define DPAD 72
#define TILE_STRIDE (64 * 3072)

__global__ __launch_bounds__(256, 6)
void attn_part(const short* __restrict__ QKV, short* __restrict__ Po,
               float* __restrict__ Pm) {
    __shared__ short Ksm[2][4096];      // K[kv][d] linear 64x64, XOR-swizzled content
    __shared__ short Vsm[64 * DPAD];    // V^T[d][kv] single buffer

    const int tid  = threadIdx.x;
    const int lane = tid & 63;
    const int l15  = lane & 15;
    const int lq   = lane >> 4;
    const int wave = tid >> 6;
    const int bh = blockIdx.y;
    const int b = bh >> 4, h = bh & 15;
    const int u = blockIdx.x;

    int qt, t0, t1;
    if (u < 16)      { qt = u + 16; t0 = 0;  t1 = 16; }
    else if (u < 32) { qt = 47 - u; t0 = 16; t1 = qt + 1; }
    else             { qt = 47 - u; t0 = 0;  t1 = qt + 1; }
    const bool hasDiag = (t1 - 1 == qt);
    const int q0 = qt * 64;

    const short* base = QKV + (size_t)b * 2048 * 3072 + h * 192;

    // --- K staging: global_load_lds, pre-swizzled source, linear dest ---
    const int trow = tid >> 3;                                   // 0..31
    const int kgoff = trow * 3072 + 64 + ((((tid & 7) ^ (trow & 7))) << 3);
    const short* kgp = base + (size_t)t0 * TILE_STRIDE + kgoff;
    auto kstage = [&](const short* src, int bb) {
        async_ld16(src,             &Ksm[bb][wave * 512]);
        async_ld16(src + 32 * 3072, &Ksm[bb][2048 + wave * 512]);
    };
    // swizzled K read offsets (lane-constant); row byte base = l15*128
    const int s3 = l15 & 7;
    const int kro0 = l15 * 64 + ((lq ^ s3) << 3);         // d-group lq
    const int kro1 = l15 * 64 + (((lq + 4) ^ s3) << 3);   // d-group lq+4 (XOR, not +32!)

    // --- V staging: reg-load pair of rows, packed-dword transpose write ---
    const int r2 = tid & 31;
    const int d0 = (tid >> 5) << 3;
    const short* vgp = base + (size_t)t0 * TILE_STRIDE + (size_t)(2 * r2) * 3072 + 128 + d0;
    bf16x8 vreg[2];
    auto vload = [&]() {
        vreg[0] = *(const bf16x8*)vgp;
        vreg[1] = *(const bf16x8*)(vgp + 3072);
    };
    auto vwrite = [&]() {
#pragma unroll
        for (int j = 0; j < 8; ++j) {
            union { uint16_t s[2]; uint32_t u32; } w;
            w.s[0] = (uint16_t)vreg[0][j];
            w.s[1] = (uint16_t)vreg[1][j];
            *(uint32_t*)&Vsm[(d0 + j) * DPAD + 2 * r2] = w.u32;
        }
    };

    const float SCALE2 = 0.03125f * 1.44269504f;  // 1/sqrt(1024) * log2(e)

    // bpermute byte-addresses for P redistribution (lane-constant)
    const int addrA = ((((2 * lq) & 3) << 4) + l15) << 2;
    const int addrB = ((((2 * lq + 1) & 3) << 4) + l15) << 2;
    const bool hi2 = (lq >> 1) != 0;

    // --- Q: load + pre-scale by SCALE2 (once per block) ---
    bf16x8 qf[2];
    {
        const short* qp = base + (size_t)(q0 + wave * 16 + l15) * 3072 + (lq << 3);
        bf16x8 r0 = *(const bf16x8*)qp;
        bf16x8 r1 = *(const bf16x8*)(qp + 32);
#pragma unroll
        for (int j = 0; j < 8; ++j) {
            qf[0][j] = f2bf(bf2f(r0[j]) * SCALE2);
            qf[1][j] = f2bf(bf2f(r1[j]) * SCALE2);
        }
    }

    f32x4 o[4];
#pragma unroll
    for (int n = 0; n < 4; ++n) o[n] = (f32x4)(0.0f);
    float m_run = -1e30f, l_run = 0.f;

    const int qg = q0 + wave * 16 + l15;

    auto tile_body = [&](int bb, int kv0, bool DIAG) {
        // swapped QK^T from swizzled Ksm: lane holds q=l15, kv = n*16+lq*4+r
        float p[4][4];
#pragma unroll
        for (int n = 0; n < 4; ++n) {
            bf16x8 k0 = *(const bf16x8*)&Ksm[bb][kro0 + n * 1024];
            bf16x8 k1 = *(const bf16x8*)&Ksm[bb][kro1 + n * 1024];
            f32x4 z = (f32x4)(0.0f);
            z = MFMA16(k0, qf[0], z);
            z = MFMA16(k1, qf[1], z);
#pragma unroll
            for (int r = 0; r < 4; ++r) p[n][r] = z[r];
        }

        if (DIAG) {
#pragma unroll
            for (int n = 0; n < 4; ++n)
#pragma unroll
                for (int r = 0; r < 4; ++r)
                    if ((kv0 + n * 16 + (lq << 2) + r) > qg) p[n][r] = -1e30f;
        }

        float m01 = fmaxf(fmaxf(p[0][0], p[0][1]), fmaxf(p[0][2], p[0][3]));
        float m23 = fmaxf(fmaxf(p[1][0], p[1][1]), fmaxf(p[1][2], p[1][3]));
        float m45 = fmaxf(fmaxf(p[2][0], p[2][1]), fmaxf(p[2][2], p[2][3]));
        float m67 = fmaxf(fmaxf(p[3][0], p[3][1]), fmaxf(p[3][2], p[3][3]));
        float mx = fmaxf(fmaxf(m01, m23), fmaxf(m45, m67));
        mx = fmaxf(mx, __shfl_xor(mx, 16, 64));
        mx = fmaxf(mx, __shfl_xor(mx, 32, 64));

        if (!__all(mx <= m_run + 8.f)) {          // T13 defer-rescale
            const float mnew = fmaxf(m_run, mx);
            const float corr = exp2f(m_run - mnew);
            l_run *= corr;
#pragma unroll
            for (int n = 0; n < 4; ++n) o[n] *= corr;
            m_run = mnew;
        }

        float ps = 0.f;
#pragma unroll
        for (int n = 0; n < 4; ++n)
#pragma unroll
            for (int r = 0; r < 4; ++r) {
                p[n][r] = exp2f(p[n][r] - m_run);
                ps += p[n][r];
            }
        ps += __shfl_xor(ps, 16, 64);
        ps += __shfl_xor(ps, 32, 64);
        l_run += ps;

        uint32_t wv[4][2];
#pragma unroll
        for (int n = 0; n < 4; ++n)
#pragma unroll
            for (int v = 0; v < 2; ++v)
                asm("v_cvt_pk_bf16_f32 %0, %1, %2"
                    : "=v"(wv[n][v]) : "v"(p[n][2 * v]), "v"(p[n][2 * v + 1]));

        uint32_t W0[4], W1[4];
#pragma unroll
        for (int jw = 0; jw < 4; ++jw) {
            const int addr = (jw < 2) ? addrA : addrB;
            const int uu = jw & 1;
            int f0 = __builtin_amdgcn_ds_bpermute(addr, (int)wv[0][uu]);
            int f1 = __builtin_amdgcn_ds_bpermute(addr, (int)wv[1][uu]);
            W0[jw] = hi2 ? (uint32_t)f1 : (uint32_t)f0;
            int g0 = __builtin_amdgcn_ds_bpermute(addr, (int)wv[2][uu]);
            int g1 = __builtin_amdgcn_ds_bpermute(addr, (int)wv[3][uu]);
            W1[jw] = hi2 ? (uint32_t)g1 : (uint32_t)g0;
        }
        union { uint32_t u32[4]; bf16x8 v; } pb0, pb1;
#pragma unroll
        for (int i = 0; i < 4; ++i) { pb0.u32[i] = W0[i]; pb1.u32[i] = W1[i]; }

        // PV: O^T[d][q] += V^T . P^T
#pragma unroll
        for (int n = 0; n < 4; ++n) {
            const short* vp = &Vsm[(n * 16 + l15) * DPAD + (lq << 3)];
            bf16x8 v0 = *(const bf16x8*)vp;
            bf16x8 v1 = *(const bf16x8*)(vp + 32);
            o[n] = MFMA16(v0, pb0.v, o[n]);
            o[n] = MFMA16(v1, pb1.v, o[n]);
        }
    };

    // prologue: stage tile t0
    kstage(kgp, 0);
    vload();
    vwrite();
    __syncthreads();     // K gload drained (vmcnt) + V visible
    int cur = 0;

#pragma unroll 1
    for (int t = t0; t < t1 - 1; ++t) {
        kgp += TILE_STRIDE;
        vgp += TILE_STRIDE;
        kstage(kgp, cur ^ 1);          // async K(t+1), lands under compute
        vload();                        // V(t+1) -> regs, lands under compute
        tile_body(cur, t * 64, false);
        __syncthreads();               // PV readers of Vsm done
        vwrite();                      // Vsm = V(t+1)
        __syncthreads();               // V visible + K(t+1) drained
        cur ^= 1;
    }
    if (hasDiag) tile_body(cur, (t1 - 1) * 64, true);
    else         tile_body(cur, (t1 - 1) * 64, false);

    // epilogue: normalized bf16 partial + fp32 lse
    const float inv = 1.f / l_run;
    const int prow = (bh * 48 + u) * 64 + wave * 16 + l15;
#pragma unroll
    for (int n = 0; n < 4; ++n) {
        bf16x4 w;
#pragma unroll
        for (int j = 0; j < 4; ++j) w[j] = f2bf(o[n][j] * inv);
        *(bf16x4*)&Po[(size_t)prow * 64 + n * 16 + (lq << 2)] = w;
    }
    if (lq == 0) Pm[prow] = m_run + __log2f(l_run);
}

// ---------------------------------------------------------------------------
// attn_combine: merge <=2 partials per q-row -> fp32 Out [B,H,S,64] flat.
// ---------------------------------------------------------------------------
__global__ __launch_bounds__(256)
void attn_combine(const short* __restrict__ Po, const float* __restrict__ Pm,
                  float* __restrict__ Out) {
    const int idx = blockIdx.x * 256 + threadIdx.x;
    const int d4 = (idx & 15) << 2;
    const int rg = idx >> 4;
    const int q  = rg & 2047;
    const int bh = rg >> 11;
    const int qt = q >> 6, r = q & 63;

    f32x4 ov;
    if (qt < 16) {
        const int p0 = (bh * 48 + (47 - qt)) * 64 + r;
        bf16x4 a = *(const bf16x4*)&Po[(size_t)p0 * 64 + d4];
#pragma unroll
        for (int j = 0; j < 4; ++j) ov[j] = bf2f(a[j]);
    } else {
        const int p0 = (bh * 48 + (qt - 16)) * 64 + r;
        const int p1 = (bh * 48 + (47 - qt)) * 64 + r;
        bf16x4 a = *(const bf16x4*)&Po[(size_t)p0 * 64 + d4];
        bf16x4 c = *(const bf16x4*)&Po[(size_t)p1 * 64 + d4];
        const float m0 = Pm[p0], m1 = Pm[p1];
        const float M = fmaxf(m0, m1);
        const float w0 = exp2f(m0 - M), w1 = exp2f(m1 - M);
        const float inv = 1.f / (w0 + w1);
#pragma unroll
        for (int j = 0; j < 4; ++j) ov[j] = (w0 * bf2f(a[j]) + w1 * bf2f(c[j])) * inv;
    }
    *(f32x4*)&Out[(size_t)rg * 64 + d4] = ov;
}

extern "C" void kernel_launch(void* const* d_in, const int* in_sizes, int n_in,
                              void* d_out, int out_size, void* d_ws, size_t ws_size,
                              hipStream_t stream) {
    const float* x  = (const float*)d_in[0];
    const float* W0 = (const float*)d_in[1];
    const float* b0 = (const float*)d_in[2];
    float* out = (float*)d_out;
    char* ws = (char*)d_ws;

    const size_t QKV_B = (size_t)4096 * 3072 * 2;     // 25.17 MB
    const size_t XBF_B = (size_t)4096 * 1024 * 2;     // 8.39 MB
    const size_t PO_B  = (size_t)1536 * 64 * 64 * 2;  // 12.58 MB

    short* qkv = (short*)ws;
    short* xb  = (short*)(ws + QKV_B);
    short* wt  = (short*)(ws + QKV_B + XBF_B);
    short* po  = (short*)(ws + QKV_B);                // reuse xb/wt after gemm
    float* pm  = (float*)(ws + QKV_B + PO_B);

    convert_x<<<dim3(2048), dim3(256), 0, stream>>>(x, xb);
    convert_wt<<<dim3(48, 16), dim3(256), 0, stream>>>(W0, wt);
    gemm_bf16<<<dim3(768), dim3(256), 0, stream>>>(xb, wt, b0, qkv);
    attn_part<<<dim3(48, 32), dim3(256), 0, stream>>>(qkv, po, pm);
    attn_combine<<<dim3(4096), dim3(256), 0, stream>>>(po, pm, out);
}

// Round 9
// 107.761 us; speedup vs baseline: 1.1880x; 1.0723x over previous
//
#include <hip/hip_runtime.h>
#include <stdint.h>

typedef __attribute__((ext_vector_type(4))) float f32x4;
typedef __attribute__((ext_vector_type(16))) float f32x16;
typedef __attribute__((ext_vector_type(8))) short bf16x8;
typedef __attribute__((ext_vector_type(4))) short bf16x4;

#define MFMA16(a, b, c) __builtin_amdgcn_mfma_f32_16x16x32_bf16((a), (b), (c), 0, 0, 0)
#define MFMA32(a, b, c) __builtin_amdgcn_mfma_f32_32x32x16_bf16((a), (b), (c), 0, 0, 0)

__device__ __forceinline__ short f2bf(float f) {
    union { float f; uint32_t u; } v; v.f = f;
    uint32_t r = (v.u + 0x7fffu + ((v.u >> 16) & 1u)) >> 16;
    return (short)(uint16_t)r;
}
__device__ __forceinline__ float bf2f(short s) {
    union { uint32_t u; float f; } v; v.u = ((uint32_t)(uint16_t)s) << 16;
    return v.f;
}

__device__ __forceinline__ void async_ld16(const short* g, short* l) {
    __builtin_amdgcn_global_load_lds(
        (const __attribute__((address_space(1))) uint32_t*)g,
        (__attribute__((address_space(3))) uint32_t*)l, 16, 0, 0);
}

// pack 8 exp'd P-values (regs O..O+7 of accumulator C) into the 32x32 B-frag
// for one kvslot, exchanging halves between lane and lane+32 via permlane32_swap.
// After swap(a,b): word0=a, word2=b valid for BOTH hi-halves (see derivation).
#define MK_BFRAG(C, O, OUT) do {                                                   \
    uint32_t a_, b_, c_, d_;                                                       \
    asm("v_cvt_pk_bf16_f32 %0, %1, %2" : "=v"(a_) : "v"((C)[(O)+0]), "v"((C)[(O)+1])); \
    asm("v_cvt_pk_bf16_f32 %0, %1, %2" : "=v"(c_) : "v"((C)[(O)+2]), "v"((C)[(O)+3])); \
    asm("v_cvt_pk_bf16_f32 %0, %1, %2" : "=v"(b_) : "v"((C)[(O)+4]), "v"((C)[(O)+5])); \
    asm("v_cvt_pk_bf16_f32 %0, %1, %2" : "=v"(d_) : "v"((C)[(O)+6]), "v"((C)[(O)+7])); \
    asm("v_permlane32_swap_b32 %0, %1" : "+v"(a_), "+v"(b_));                      \
    asm("v_permlane32_swap_b32 %0, %1" : "+v"(c_), "+v"(d_));                      \
    union { uint32_t u[4]; bf16x8 v; } pb_;                                        \
    pb_.u[0] = a_; pb_.u[1] = c_; pb_.u[2] = b_; pb_.u[3] = d_;                    \
    OUT = pb_.v;                                                                   \
} while (0)

// ---------------------------------------------------------------------------
// convert_x: X fp32 [4096*1024] -> bf16
// ---------------------------------------------------------------------------
__global__ __launch_bounds__(256)
void convert_x(const float* __restrict__ X, short* __restrict__ Xb) {
    const int i8 = (blockIdx.x * 256 + threadIdx.x) << 3;
    f32x4 a = *(const f32x4*)(X + i8);
    f32x4 b = *(const f32x4*)(X + i8 + 4);
    bf16x8 o;
#pragma unroll
    for (int j = 0; j < 4; ++j) { o[j] = f2bf(a[j]); o[4 + j] = f2bf(b[j]); }
    *(bf16x8*)(Xb + i8) = o;
}

// ---------------------------------------------------------------------------
// convert_wt: W fp32 [1024][3072] -> Wt bf16 [3072][1024]
// ---------------------------------------------------------------------------
__global__ __launch_bounds__(256)
void convert_wt(const float* __restrict__ W, short* __restrict__ Wt) {
    __shared__ short T[64][72];
    const int t = threadIdx.x;
    const int n0 = blockIdx.x * 64, k0 = blockIdx.y * 64;
#pragma unroll
    for (int i = 0; i < 4; ++i) {
        const int r = i * 16 + (t >> 4);
        const int c = (t & 15) << 2;
        f32x4 v = *(const f32x4*)(W + (size_t)(k0 + r) * 3072 + n0 + c);
#pragma unroll
        for (int j = 0; j < 4; ++j) T[c + j][r] = f2bf(v[j]);
    }
    __syncthreads();
#pragma unroll
    for (int i = 0; i < 2; ++i) {
        const int r = i * 32 + (t >> 3);
        const int c = (t & 7) << 3;
        *(bf16x8*)(Wt + (size_t)(n0 + r) * 1024 + k0 + c) = *(const bf16x8*)&T[r][c];
    }
}

// ---------------------------------------------------------------------------
// gemm_bf16 (m97 structure): QKV = Xb @ Wt^T + bias, output bf16  (unchanged)
// ---------------------------------------------------------------------------
__global__ __launch_bounds__(256, 2)
void gemm_bf16(const short* __restrict__ Xb, const short* __restrict__ Wt,
               const float* __restrict__ bias, short* __restrict__ QKV) {
    __shared__ short Asm[2][128 * 32];
    __shared__ short Bsm[2][128 * 32];

    const int tid  = threadIdx.x;
    const int lane = tid & 63;
    const int l15  = lane & 15;
    const int lq   = lane >> 4;
    const int wave = tid >> 6;
    const int wr = wave >> 1, wc = wave & 1;

    const int bid = blockIdx.x;
    const int swz = (bid & 7) * 96 + (bid >> 3);
    const int m0 = (swz / 24) * 128, n0 = (swz % 24) * 128;

    const int srow = tid >> 2;
    const int scol = (tid & 3) << 3;

    f32x4 acc[4][4];
#pragma unroll
    for (int m = 0; m < 4; ++m)
#pragma unroll
        for (int n = 0; n < 4; ++n) acc[m][n] = (f32x4)(0.0f);

    auto stage = [&](int k0, int bb) {
#pragma unroll
        for (int i = 0; i < 2; ++i)
            async_ld16(Xb + (size_t)(m0 + i * 64 + srow) * 1024 + k0 + scol,
                       &Asm[bb][(i * 256 + wave * 64) * 8]);
#pragma unroll
        for (int i = 0; i < 2; ++i)
            async_ld16(Wt + (size_t)(n0 + i * 64 + srow) * 1024 + k0 + scol,
                       &Bsm[bb][(i * 256 + wave * 64) * 8]);
    };

    auto compute = [&](int bb) {
        bf16x8 af[4], bfv[4];
#pragma unroll
        for (int m = 0; m < 4; ++m)
            af[m] = *(const bf16x8*)&Asm[bb][(wr * 64 + m * 16 + l15) * 32 + (lq << 3)];
#pragma unroll
        for (int n = 0; n < 4; ++n)
            bfv[n] = *(const bf16x8*)&Bsm[bb][(wc * 64 + n * 16 + l15) * 32 + (lq << 3)];
#pragma unroll
        for (int m = 0; m < 4; ++m)
#pragma unroll
            for (int n = 0; n < 4; ++n) acc[m][n] = MFMA16(af[m], bfv[n], acc[m][n]);
    };

    stage(0, 0);
    __syncthreads();
    int cur = 0;
#pragma unroll 1
    for (int kt = 0; kt < 32; ++kt) {
        if (kt + 1 < 32) stage((kt + 1) * 32, cur ^ 1);
        compute(cur);
        __syncthreads();
        cur ^= 1;
    }

    float bv[4];
#pragma unroll
    for (int n = 0; n < 4; ++n) bv[n] = bias[n0 + wc * 64 + n * 16 + l15];
#pragma unroll
    for (int m = 0; m < 4; ++m) {
        const int row = m0 + wr * 64 + m * 16 + (lq << 2);
#pragma unroll
        for (int n = 0; n < 4; ++n) {
            const int col = n0 + wc * 64 + n * 16 + l15;
#pragma unroll
            for (int r = 0; r < 4; ++r)
                QKV[(size_t)(row + r) * 3072 + col] = f2bf(acc[m][n][r] + bv[n]);
        }
    }
}

// ---------------------------------------------------------------------------
// attn_part v6: 32x32 MFMA, 2 waves x 32 q = 64 q per block; swapped QK^T
// (C: col=q=lane&31, row=kv=(reg&3)+8*(reg>>2)+4*hi); P -> PV B-frag via
// cvt_pk + permlane32_swap (no bpermute, no P LDS). K via global_load_lds
// (dbuf, XOR swizzle); V^T single-buffer reg-staged. Chunk map as R6/R8.
// ---------------------------------------------------------------------------
#define DPAD 72
#define TILE_STRIDE (64 * 3072)

__global__ __launch_bounds__(128, 3)
void attn_part(const short* __restrict__ QKV, short* __restrict__ Po,
               float* __restrict__ Pm) {
    __shared__ short Ksm[2][4096];      // K[kv][d] 64x64 linear, XOR-swizzled content
    __shared__ short Vsm[64 * DPAD];    // V^T[d][kv] single buffer

    const int tid  = threadIdx.x;       // 0..127
    const int lane = tid & 63;
    const int l31  = lane & 31;
    const int hi   = lane >> 5;
    const int wq   = tid >> 6;          // wave: q-half 0/1
    const int bh = blockIdx.y;
    const int b = bh >> 4, h = bh & 15;
    const int u = blockIdx.x;

    int qt, t0, t1;
    if (u < 16)      { qt = u + 16; t0 = 0;  t1 = 16; }
    else if (u < 32) { qt = 47 - u; t0 = 16; t1 = qt + 1; }
    else             { qt = 47 - u; t0 = 0;  t1 = qt + 1; }
    const bool hasDiag = (t1 - 1 == qt);
    const int q0 = qt * 64;

    const short* base = QKV + (size_t)b * 2048 * 3072 + h * 192;

    // --- K staging: 4 x async_ld16 per thread, pre-swizzled source ---
    const int kln = lane >> 3;                      // 0..7
    const int kcolsw = ((lane & 7) ^ kln) << 3;     // swizzled col (elems)
    const short* kgp = base + (size_t)t0 * TILE_STRIDE
                     + (size_t)(wq * 8 + kln) * 3072 + 64 + kcolsw;
    auto kstage = [&](const short* src, int bb) {
#pragma unroll
        for (int i = 0; i < 4; ++i)
            async_ld16(src + (size_t)i * 16 * 3072, &Ksm[bb][(i * 2 + wq) * 512]);
    };

    // --- V staging: thread owns kv pair (2r2,2r2+1) x 16 d's ---
    const int r2 = tid & 31;
    const int d0v = (tid >> 5) << 4;                // 0,16,32,48
    const short* vgp = base + (size_t)t0 * TILE_STRIDE
                     + (size_t)(2 * r2) * 3072 + 128 + d0v;
    bf16x8 vr00, vr01, vr10, vr11;
    auto vload = [&]() {
        vr00 = *(const bf16x8*)vgp;
        vr01 = *(const bf16x8*)(vgp + 8);
        vr10 = *(const bf16x8*)(vgp + 3072);
        vr11 = *(const bf16x8*)(vgp + 3080);
    };
    auto vwrite = [&]() {
#pragma unroll
        for (int j = 0; j < 8; ++j) {
            uint32_t wlo = (uint16_t)vr00[j] | ((uint32_t)(uint16_t)vr10[j] << 16);
            *(uint32_t*)&Vsm[(d0v + j) * DPAD + 2 * r2] = wlo;
            uint32_t whi = (uint16_t)vr01[j] | ((uint32_t)(uint16_t)vr11[j] << 16);
            *(uint32_t*)&Vsm[(d0v + 8 + j) * DPAD + 2 * r2] = whi;
        }
    };

    const float SCALE2 = 0.03125f * 1.44269504f;  // 1/sqrt(1024) * log2(e)

    // --- Q: load + pre-scale; B-frag: col=q=l31, k = dg*16 + hi*8 + j ---
    bf16x8 qf[4];
    {
        const short* qp = base + (size_t)(q0 + wq * 32 + l31) * 3072;
#pragma unroll
        for (int dg = 0; dg < 4; ++dg) {
            bf16x8 r0 = *(const bf16x8*)(qp + dg * 16 + hi * 8);
#pragma unroll
            for (int j = 0; j < 8; ++j) qf[dg][j] = f2bf(bf2f(r0[j]) * SCALE2);
        }
    }

    f32x16 o0 = (f32x16)(0.f), o1 = (f32x16)(0.f);   // O^T d=0..31 / 32..63
    float m_run = -1e30f, l_run = 0.f;
    const int qg = q0 + wq * 32 + l31;
    const int ks7 = l31 & 7;                          // K read-swizzle row bits

    auto tile_body = [&](int bb, int kv0, bool DIAG) {
        // ---- QK^T: S^T[kv][q], two 32x32 accumulators (kvgrp 0/1) ----
        f32x16 c0 = (f32x16)(0.f), c1 = (f32x16)(0.f);
#pragma unroll
        for (int dg = 0; dg < 4; ++dg) {
            const int g = ((dg * 2 + hi) ^ ks7) << 3;
            bf16x8 a0 = *(const bf16x8*)&Ksm[bb][l31 * 64 + g];
            bf16x8 a1 = *(const bf16x8*)&Ksm[bb][(32 + l31) * 64 + g];
            c0 = MFMA32(a0, qf[dg], c0);
            c1 = MFMA32(a1, qf[dg], c1);
        }

        if (DIAG) {
#pragma unroll
            for (int r = 0; r < 16; ++r) {
                const int kvr = kv0 + (r & 3) + 8 * (r >> 2) + 4 * hi;
                if (kvr > qg)      c0[r] = -1e30f;
                if (kvr + 32 > qg) c1[r] = -1e30f;
            }
        }

        // ---- row max: 31 in-lane + 1 shfl (partner lane shares q) ----
        float mr[8];
#pragma unroll
        for (int r = 0; r < 8; ++r)
            mr[r] = fmaxf(fmaxf(c0[r], c0[8 + r]), fmaxf(c1[r], c1[8 + r]));
        float mx = fmaxf(fmaxf(fmaxf(mr[0], mr[1]), fmaxf(mr[2], mr[3])),
                         fmaxf(fmaxf(mr[4], mr[5]), fmaxf(mr[6], mr[7])));
        mx = fmaxf(mx, __shfl_xor(mx, 32, 64));

        if (!__all(mx <= m_run + 8.f)) {              // T13 defer-rescale
            const float mnew = fmaxf(m_run, mx);
            const float corr = exp2f(m_run - mnew);
            l_run *= corr;
            o0 = o0 * corr;
            o1 = o1 * corr;
            m_run = mnew;
        }

        float ps = 0.f;
#pragma unroll
        for (int r = 0; r < 16; ++r) { c0[r] = exp2f(c0[r] - m_run); ps += c0[r]; }
#pragma unroll
        for (int r = 0; r < 16; ++r) { c1[r] = exp2f(c1[r] - m_run); ps += c1[r]; }
        ps += __shfl_xor(ps, 32, 64);
        l_run += ps;

        // ---- P -> B-frags (4 kvslots) via cvt_pk + permlane32_swap ----
        bf16x8 bf00, bf01, bf10, bf11;
        MK_BFRAG(c0, 0, bf00);   // kv  0..15
        MK_BFRAG(c0, 8, bf01);   // kv 16..31
        MK_BFRAG(c1, 0, bf10);   // kv 32..47
        MK_BFRAG(c1, 8, bf11);   // kv 48..63

        // ---- PV: O^T[d][q] += V^T . P^T ----
        {
            const short* vb0 = &Vsm[(size_t)l31 * DPAD];          // d = l31
            const short* vb1 = &Vsm[(size_t)(32 + l31) * DPAD];   // d = 32+l31
            const int ko = hi * 8;
            o0 = MFMA32(*(const bf16x8*)(vb0 + ko),      bf00, o0);
            o0 = MFMA32(*(const bf16x8*)(vb0 + 16 + ko), bf01, o0);
            o0 = MFMA32(*(const bf16x8*)(vb0 + 32 + ko), bf10, o0);
            o0 = MFMA32(*(const bf16x8*)(vb0 + 48 + ko), bf11, o0);
            o1 = MFMA32(*(const bf16x8*)(vb1 + ko),      bf00, o1);
            o1 = MFMA32(*(const bf16x8*)(vb1 + 16 + ko), bf01, o1);
            o1 = MFMA32(*(const bf16x8*)(vb1 + 32 + ko), bf10, o1);
            o1 = MFMA32(*(const bf16x8*)(vb1 + 48 + ko), bf11, o1);
        }
    };

    // prologue: stage tile t0
    kstage(kgp, 0);
    vload();
    vwrite();
    __syncthreads();
    int cur = 0;

#pragma unroll 1
    for (int t = t0; t < t1 - 1; ++t) {
        kgp += TILE_STRIDE;
        vgp += TILE_STRIDE;
        kstage(kgp, cur ^ 1);          // async K(t+1)
        vload();                        // V(t+1) -> regs
        tile_body(cur, (t - qt) * 64 + q0 - (qt - t) * 0 + (t * 64 - q0) * 0 + t * 64 - t * 64 + t * 64, false);
        __syncthreads();                // PV readers of Vsm done
        vwrite();
        __syncthreads();                // V visible + K(t+1) drained
        cur ^= 1;
    }
    if (hasDiag) tile_body(cur, (t1 - 1) * 64, true);
    else         tile_body(cur, (t1 - 1) * 64, false);

    // ---- epilogue: lane owns q-row, d = (r&3)+8*(r>>2)+4*hi (+32 for o1) ----
    const float inv = 1.f / l_run;
    const int prow = (bh * 48 + u) * 64 + wq * 32 + l31;
#pragma unroll
    for (int g = 0; g < 4; ++g) {
        bf16x4 w4;
#pragma unroll
        for (int j = 0; j < 4; ++j) w4[j] = f2bf(o0[g * 4 + j] * inv);
        *(bf16x4*)&Po[(size_t)prow * 64 + 8 * g + 4 * hi] = w4;
#pragma unroll
        for (int j = 0; j < 4; ++j) w4[j] = f2bf(o1[g * 4 + j] * inv);
        *(bf16x4*)&Po[(size_t)prow * 64 + 32 + 8 * g + 4 * hi] = w4;
    }
    if (hi == 0) Pm[prow] = m_run + __log2f(l_run);
}

// ---------------------------------------------------------------------------
// attn_combine: merge <=2 partials per q-row -> fp32 Out [B,H,S,64] flat.
// ---------------------------------------------------------------------------
__global__ __launch_bounds__(256)
void attn_combine(const short* __restrict__ Po, const float* __restrict__ Pm,
                  float* __restrict__ Out) {
    const int idx = blockIdx.x * 256 + threadIdx.x;
    const int d4 = (idx & 15) << 2;
    const int rg = idx >> 4;
    const int q  = rg & 2047;
    const int bh = rg >> 11;
    const int qt = q >> 6, r = q & 63;

    f32x4 ov;
    if (qt < 16) {
        const int p0 = (bh * 48 + (47 - qt)) * 64 + r;
        bf16x4 a = *(const bf16x4*)&Po[(size_t)p0 * 64 + d4];
#pragma unroll
        for (int j = 0; j < 4; ++j) ov[j] = bf2f(a[j]);
    } else {
        const int p0 = (bh * 48 + (qt - 16)) * 64 + r;
        const int p1 = (bh * 48 + (47 - qt)) * 64 + r;
        bf16x4 a = *(const bf16x4*)&Po[(size_t)p0 * 64 + d4];
        bf16x4 c = *(const bf16x4*)&Po[(size_t)p1 * 64 + d4];
        const float m0 = Pm[p0], m1 = Pm[p1];
        const float M = fmaxf(m0, m1);
        const float w0 = exp2f(m0 - M), w1 = exp2f(m1 - M);
        const float inv = 1.f / (w0 + w1);
#pragma unroll
        for (int j = 0; j < 4; ++j) ov[j] = (w0 * bf2f(a[j]) + w1 * bf2f(c[j])) * inv;
    }
    *(f32x4*)&Out[(size_t)rg * 64 + d4] = ov;
}

extern "C" void kernel_launch(void* const* d_in, const int* in_sizes, int n_in,
                              void* d_out, int out_size, void* d_ws, size_t ws_size,
                              hipStream_t stream) {
    const float* x  = (const float*)d_in[0];
    const float* W0 = (const float*)d_in[1];
    const float* b0 = (const float*)d_in[2];
    float* out = (float*)d_out;
    char* ws = (char*)d_ws;

    const size_t QKV_B = (size_t)4096 * 3072 * 2;     // 25.17 MB
    const size_t XBF_B = (size_t)4096 * 1024 * 2;     // 8.39 MB
    const size_t PO_B  = (size_t)1536 * 64 * 64 * 2;  // 12.58 MB

    short* qkv = (short*)ws;
    short* xb  = (short*)(ws + QKV_B);
    short* wt  = (short*)(ws + QKV_B + XBF_B);
    short* po  = (short*)(ws + QKV_B);                // reuse xb/wt after gemm
    float* pm  = (float*)(ws + QKV_B + PO_B);

    convert_x<<<dim3(2048), dim3(256), 0, stream>>>(x, xb);
    convert_wt<<<dim3(48, 16), dim3(256), 0, stream>>>(W0, wt);
    gemm_bf16<<<dim3(768), dim3(256), 0, stream>>>(xb, wt, b0, qkv);
    attn_part<<<dim3(48, 32), dim3(128), 0, stream>>>(qkv, po, pm);
    attn_combine<<<dim3(4096), dim3(256), 0, stream>>>(po, pm, out);
}

// Round 10
// 106.131 us; speedup vs baseline: 1.2062x; 1.0154x over previous
//
#include <hip/hip_runtime.h>
#include <stdint.h>

typedef __attribute__((ext_vector_type(4))) float f32x4;
typedef __attribute__((ext_vector_type(16))) float f32x16;
typedef __attribute__((ext_vector_type(8))) short bf16x8;
typedef __attribute__((ext_vector_type(4))) short bf16x4;

#define MFMA16(a, b, c) __builtin_amdgcn_mfma_f32_16x16x32_bf16((a), (b), (c), 0, 0, 0)
#define MFMA32(a, b, c) __builtin_amdgcn_mfma_f32_32x32x16_bf16((a), (b), (c), 0, 0, 0)

__device__ __forceinline__ short f2bf(float f) {
    union { float f; uint32_t u; } v; v.f = f;
    uint32_t r = (v.u + 0x7fffu + ((v.u >> 16) & 1u)) >> 16;
    return (short)(uint16_t)r;
}
__device__ __forceinline__ float bf2f(short s) {
    union { uint32_t u; float f; } v; v.u = ((uint32_t)(uint16_t)s) << 16;
    return v.f;
}

__device__ __forceinline__ void async_ld16(const short* g, short* l) {
    __builtin_amdgcn_global_load_lds(
        (const __attribute__((address_space(1))) uint32_t*)g,
        (__attribute__((address_space(3))) uint32_t*)l, 16, 0, 0);
}

// pack 8 exp'd P-values (regs O..O+7 of accumulator C) into the 32x32 B-frag
// for one kvslot via cvt_pk + permlane32_swap (lane<->lane+32 half exchange).
#define MK_BFRAG(C, O, OUT) do {                                                   \
    uint32_t a_, b_, c_, d_;                                                       \
    asm("v_cvt_pk_bf16_f32 %0, %1, %2" : "=v"(a_) : "v"((C)[(O)+0]), "v"((C)[(O)+1])); \
    asm("v_cvt_pk_bf16_f32 %0, %1, %2" : "=v"(c_) : "v"((C)[(O)+2]), "v"((C)[(O)+3])); \
    asm("v_cvt_pk_bf16_f32 %0, %1, %2" : "=v"(b_) : "v"((C)[(O)+4]), "v"((C)[(O)+5])); \
    asm("v_cvt_pk_bf16_f32 %0, %1, %2" : "=v"(d_) : "v"((C)[(O)+6]), "v"((C)[(O)+7])); \
    asm("v_permlane32_swap_b32 %0, %1" : "+v"(a_), "+v"(b_));                      \
    asm("v_permlane32_swap_b32 %0, %1" : "+v"(c_), "+v"(d_));                      \
    union { uint32_t u[4]; bf16x8 v; } pb_;                                        \
    pb_.u[0] = a_; pb_.u[1] = c_; pb_.u[2] = b_; pb_.u[3] = d_;                    \
    OUT = pb_.v;                                                                   \
} while (0)

// ---------------------------------------------------------------------------
// convert_x: X fp32 [4096*1024] -> bf16
// ---------------------------------------------------------------------------
__global__ __launch_bounds__(256)
void convert_x(const float* __restrict__ X, short* __restrict__ Xb) {
    const int i8 = (blockIdx.x * 256 + threadIdx.x) << 3;
    f32x4 a = *(const f32x4*)(X + i8);
    f32x4 b = *(const f32x4*)(X + i8 + 4);
    bf16x8 o;
#pragma unroll
    for (int j = 0; j < 4; ++j) { o[j] = f2bf(a[j]); o[4 + j] = f2bf(b[j]); }
    *(bf16x8*)(Xb + i8) = o;
}

// ---------------------------------------------------------------------------
// convert_wt: W fp32 [1024][3072] -> Wt bf16 [3072][1024]
// ---------------------------------------------------------------------------
__global__ __launch_bounds__(256)
void convert_wt(const float* __restrict__ W, short* __restrict__ Wt) {
    __shared__ short T[64][72];
    const int t = threadIdx.x;
    const int n0 = blockIdx.x * 64, k0 = blockIdx.y * 64;
#pragma unroll
    for (int i = 0; i < 4; ++i) {
        const int r = i * 16 + (t >> 4);
        const int c = (t & 15) << 2;
        f32x4 v = *(const f32x4*)(W + (size_t)(k0 + r) * 3072 + n0 + c);
#pragma unroll
        for (int j = 0; j < 4; ++j) T[c + j][r] = f2bf(v[j]);
    }
    __syncthreads();
#pragma unroll
    for (int i = 0; i < 2; ++i) {
        const int r = i * 32 + (t >> 3);
        const int c = (t & 7) << 3;
        *(bf16x8*)(Wt + (size_t)(n0 + r) * 1024 + k0 + c) = *(const bf16x8*)&T[r][c];
    }
}

// ---------------------------------------------------------------------------
// gemm_bf16 (m97 structure): QKV = Xb @ Wt^T + bias, output bf16  (unchanged)
// ---------------------------------------------------------------------------
__global__ __launch_bounds__(256, 2)
void gemm_bf16(const short* __restrict__ Xb, const short* __restrict__ Wt,
               const float* __restrict__ bias, short* __restrict__ QKV) {
    __shared__ short Asm[2][128 * 32];
    __shared__ short Bsm[2][128 * 32];

    const int tid  = threadIdx.x;
    const int lane = tid & 63;
    const int l15  = lane & 15;
    const int lq   = lane >> 4;
    const int wave = tid >> 6;
    const int wr = wave >> 1, wc = wave & 1;

    const int bid = blockIdx.x;
    const int swz = (bid & 7) * 96 + (bid >> 3);
    const int m0 = (swz / 24) * 128, n0 = (swz % 24) * 128;

    const int srow = tid >> 2;
    const int scol = (tid & 3) << 3;

    f32x4 acc[4][4];
#pragma unroll
    for (int m = 0; m < 4; ++m)
#pragma unroll
        for (int n = 0; n < 4; ++n) acc[m][n] = (f32x4)(0.0f);

    auto stage = [&](int k0, int bb) {
#pragma unroll
        for (int i = 0; i < 2; ++i)
            async_ld16(Xb + (size_t)(m0 + i * 64 + srow) * 1024 + k0 + scol,
                       &Asm[bb][(i * 256 + wave * 64) * 8]);
#pragma unroll
        for (int i = 0; i < 2; ++i)
            async_ld16(Wt + (size_t)(n0 + i * 64 + srow) * 1024 + k0 + scol,
                       &Bsm[bb][(i * 256 + wave * 64) * 8]);
    };

    auto compute = [&](int bb) {
        bf16x8 af[4], bfv[4];
#pragma unroll
        for (int m = 0; m < 4; ++m)
            af[m] = *(const bf16x8*)&Asm[bb][(wr * 64 + m * 16 + l15) * 32 + (lq << 3)];
#pragma unroll
        for (int n = 0; n < 4; ++n)
            bfv[n] = *(const bf16x8*)&Bsm[bb][(wc * 64 + n * 16 + l15) * 32 + (lq << 3)];
#pragma unroll
        for (int m = 0; m < 4; ++m)
#pragma unroll
            for (int n = 0; n < 4; ++n) acc[m][n] = MFMA16(af[m], bfv[n], acc[m][n]);
    };

    stage(0, 0);
    __syncthreads();
    int cur = 0;
#pragma unroll 1
    for (int kt = 0; kt < 32; ++kt) {
        if (kt + 1 < 32) stage((kt + 1) * 32, cur ^ 1);
        compute(cur);
        __syncthreads();
        cur ^= 1;
    }

    float bv[4];
#pragma unroll
    for (int n = 0; n < 4; ++n) bv[n] = bias[n0 + wc * 64 + n * 16 + l15];
#pragma unroll
    for (int m = 0; m < 4; ++m) {
        const int row = m0 + wr * 64 + m * 16 + (lq << 2);
#pragma unroll
        for (int n = 0; n < 4; ++n) {
            const int col = n0 + wc * 64 + n * 16 + l15;
#pragma unroll
            for (int r = 0; r < 4; ++r)
                QKV[(size_t)(row + r) * 3072 + col] = f2bf(acc[m][n][r] + bv[n]);
        }
    }
}

// ---------------------------------------------------------------------------
// attn_part v7: 32x32 MFMA, 2 waves x 32 q. CU-balanced chunk map:
//   u<16 : qt=u+16, tiles [0,16)      (16 tiles, no diagonal)
//   u<32 : qt=47-u, tiles [16,qt+1)   (16..1 tiles, diagonal)
//   else : qt=u-32, tiles [0,qt+1)    (1..16 tiles, diagonal)
// => every u-triple {a, a+16, a+32} = 16+(16-a)+(a+1) = 33 tiles -> CUs balanced.
// ---------------------------------------------------------------------------
#define DPAD 72
#define TILE_STRIDE (64 * 3072)

__global__ __launch_bounds__(128, 3)
void attn_part(const short* __restrict__ QKV, short* __restrict__ Po,
               float* __restrict__ Pm) {
    __shared__ short Ksm[2][4096];      // K[kv][d] 64x64 linear, XOR-swizzled content
    __shared__ short Vsm[64 * DPAD];    // V^T[d][kv] single buffer

    const int tid  = threadIdx.x;       // 0..127
    const int lane = tid & 63;
    const int l31  = lane & 31;
    const int hi   = lane >> 5;
    const int wq   = tid >> 6;          // wave: q-half 0/1
    const int bh = blockIdx.y;
    const int b = bh >> 4, h = bh & 15;
    const int u = blockIdx.x;

    int qt, t0, t1;
    if (u < 16)      { qt = u + 16; t0 = 0;  t1 = 16; }
    else if (u < 32) { qt = 47 - u; t0 = 16; t1 = qt + 1; }
    else             { qt = u - 32; t0 = 0;  t1 = qt + 1; }
    const bool hasDiag = (t1 - 1 == qt);
    const int q0 = qt * 64;

    const short* base = QKV + (size_t)b * 2048 * 3072 + h * 192;

    // --- K staging: 4 x async_ld16 per thread, pre-swizzled source ---
    const int kln = lane >> 3;                      // 0..7
    const int kcolsw = ((lane & 7) ^ kln) << 3;     // swizzled col (elems)
    const short* kgp = base + (size_t)t0 * TILE_STRIDE
                     + (size_t)(wq * 8 + kln) * 3072 + 64 + kcolsw;
    auto kstage = [&](const short* src, int bb) {
#pragma unroll
        for (int i = 0; i < 4; ++i)
            async_ld16(src + (size_t)i * 16 * 3072, &Ksm[bb][(i * 2 + wq) * 512]);
    };

    // --- V staging: thread owns kv pair (2r2,2r2+1) x 16 d's ---
    const int r2 = tid & 31;
    const int d0v = (tid >> 5) << 4;                // 0,16,32,48
    const short* vgp = base + (size_t)t0 * TILE_STRIDE
                     + (size_t)(2 * r2) * 3072 + 128 + d0v;
    bf16x8 vr00, vr01, vr10, vr11;
    auto vload = [&]() {
        vr00 = *(const bf16x8*)vgp;
        vr01 = *(const bf16x8*)(vgp + 8);
        vr10 = *(const bf16x8*)(vgp + 3072);
        vr11 = *(const bf16x8*)(vgp + 3080);
    };
    auto vwrite = [&]() {
#pragma unroll
        for (int j = 0; j < 8; ++j) {
            uint32_t wlo = (uint16_t)vr00[j] | ((uint32_t)(uint16_t)vr10[j] << 16);
            *(uint32_t*)&Vsm[(d0v + j) * DPAD + 2 * r2] = wlo;
            uint32_t whi = (uint16_t)vr01[j] | ((uint32_t)(uint16_t)vr11[j] << 16);
            *(uint32_t*)&Vsm[(d0v + 8 + j) * DPAD + 2 * r2] = whi;
        }
    };

    const float SCALE2 = 0.03125f * 1.44269504f;  // 1/sqrt(1024) * log2(e)

    // --- Q: load + pre-scale; B-frag: col=q=l31, k = dg*16 + hi*8 + j ---
    bf16x8 qf[4];
    {
        const short* qp = base + (size_t)(q0 + wq * 32 + l31) * 3072;
#pragma unroll
        for (int dg = 0; dg < 4; ++dg) {
            bf16x8 r0 = *(const bf16x8*)(qp + dg * 16 + hi * 8);
#pragma unroll
            for (int j = 0; j < 8; ++j) qf[dg][j] = f2bf(bf2f(r0[j]) * SCALE2);
        }
    }

    f32x16 o0 = (f32x16)(0.f), o1 = (f32x16)(0.f);   // O^T d=0..31 / 32..63
    float m_run = -1e30f, l_run = 0.f;                // l_run is PER-LANE now
    const int qg = q0 + wq * 32 + l31;
    const int ks7 = l31 & 7;                          // K read-swizzle row bits

    auto tile_body = [&](int bb, int kv0, bool DIAG) {
        // ---- QK^T: S^T[kv][q], two 32x32 accumulators (kvgrp 0/1) ----
        f32x16 c0 = (f32x16)(0.f), c1 = (f32x16)(0.f);
#pragma unroll
        for (int dg = 0; dg < 4; ++dg) {
            const int g = ((dg * 2 + hi) ^ ks7) << 3;
            bf16x8 a0 = *(const bf16x8*)&Ksm[bb][l31 * 64 + g];
            bf16x8 a1 = *(const bf16x8*)&Ksm[bb][(32 + l31) * 64 + g];
            c0 = MFMA32(a0, qf[dg], c0);
            c1 = MFMA32(a1, qf[dg], c1);
        }

        if (DIAG) {
#pragma unroll
            for (int r = 0; r < 16; ++r) {
                const int kvr = kv0 + (r & 3) + 8 * (r >> 2) + 4 * hi;
                if (kvr > qg)      c0[r] = -1e30f;
                if (kvr + 32 > qg) c1[r] = -1e30f;
            }
        }

        // ---- row max: tree in-lane + 1 shfl (partner lane shares q) ----
        float mr[8];
#pragma unroll
        for (int r = 0; r < 8; ++r)
            mr[r] = fmaxf(fmaxf(c0[r], c0[8 + r]), fmaxf(c1[r], c1[8 + r]));
        float mx = fmaxf(fmaxf(fmaxf(mr[0], mr[1]), fmaxf(mr[2], mr[3])),
                         fmaxf(fmaxf(mr[4], mr[5]), fmaxf(mr[6], mr[7])));
        mx = fmaxf(mx, __shfl_xor(mx, 32, 64));

        if (!__all(mx <= m_run + 8.f)) {              // T13 defer-rescale
            const float mnew = fmaxf(m_run, mx);
            const float corr = exp2f(m_run - mnew);
            l_run *= corr;
            o0 = o0 * corr;
            o1 = o1 * corr;
            m_run = mnew;
        }

        // exp + tree-sum (4 independent accumulators; no serial 32-chain)
        float ps0 = 0.f, ps1 = 0.f, ps2 = 0.f, ps3 = 0.f;
#pragma unroll
        for (int r = 0; r < 4; ++r) {
            c0[r]      = exp2f(c0[r]      - m_run); ps0 += c0[r];
            c0[4 + r]  = exp2f(c0[4 + r]  - m_run); ps1 += c0[4 + r];
            c0[8 + r]  = exp2f(c0[8 + r]  - m_run); ps2 += c0[8 + r];
            c0[12 + r] = exp2f(c0[12 + r] - m_run); ps3 += c0[12 + r];
        }
#pragma unroll
        for (int r = 0; r < 4; ++r) {
            c1[r]      = exp2f(c1[r]      - m_run); ps0 += c1[r];
            c1[4 + r]  = exp2f(c1[4 + r]  - m_run); ps1 += c1[4 + r];
            c1[8 + r]  = exp2f(c1[8 + r]  - m_run); ps2 += c1[8 + r];
            c1[12 + r] = exp2f(c1[12 + r] - m_run); ps3 += c1[12 + r];
        }
        l_run += (ps0 + ps1) + (ps2 + ps3);           // per-lane; merged at epilogue

        // ---- P -> B-frags (4 kvslots) via cvt_pk + permlane32_swap ----
        bf16x8 bf00, bf01, bf10, bf11;
        MK_BFRAG(c0, 0, bf00);   // kv  0..15
        MK_BFRAG(c0, 8, bf01);   // kv 16..31
        MK_BFRAG(c1, 0, bf10);   // kv 32..47
        MK_BFRAG(c1, 8, bf11);   // kv 48..63

        // ---- PV: O^T[d][q] += V^T . P^T ----
        {
            const short* vb0 = &Vsm[(size_t)l31 * DPAD];          // d = l31
            const short* vb1 = &Vsm[(size_t)(32 + l31) * DPAD];   // d = 32+l31
            const int ko = hi * 8;
            o0 = MFMA32(*(const bf16x8*)(vb0 + ko),      bf00, o0);
            o0 = MFMA32(*(const bf16x8*)(vb0 + 16 + ko), bf01, o0);
            o0 = MFMA32(*(const bf16x8*)(vb0 + 32 + ko), bf10, o0);
            o0 = MFMA32(*(const bf16x8*)(vb0 + 48 + ko), bf11, o0);
            o1 = MFMA32(*(const bf16x8*)(vb1 + ko),      bf00, o1);
            o1 = MFMA32(*(const bf16x8*)(vb1 + 16 + ko), bf01, o1);
            o1 = MFMA32(*(const bf16x8*)(vb1 + 32 + ko), bf10, o1);
            o1 = MFMA32(*(const bf16x8*)(vb1 + 48 + ko), bf11, o1);
        }
    };

    // prologue: stage tile t0
    kstage(kgp, 0);
    vload();
    vwrite();
    __syncthreads();
    int cur = 0;

#pragma unroll 1
    for (int t = t0; t < t1 - 1; ++t) {
        kgp += TILE_STRIDE;
        vgp += TILE_STRIDE;
        kstage(kgp, cur ^ 1);          // async K(t+1)
        vload();                        // V(t+1) -> regs
        tile_body(cur, t * 64, false);
        __syncthreads();                // PV readers of Vsm done
        vwrite();
        __syncthreads();                // V visible + K(t+1) drained
        cur ^= 1;
    }
    if (hasDiag) tile_body(cur, (t1 - 1) * 64, true);
    else         tile_body(cur, (t1 - 1) * 64, false);

    // ---- epilogue: merge partner-lane l; lane owns q-row ----
    const float l_tot = l_run + __shfl_xor(l_run, 32, 64);
    const float inv = 1.f / l_tot;
    const int prow = (bh * 48 + u) * 64 + wq * 32 + l31;
#pragma unroll
    for (int g = 0; g < 4; ++g) {
        bf16x4 w4;
#pragma unroll
        for (int j = 0; j < 4; ++j) w4[j] = f2bf(o0[g * 4 + j] * inv);
        *(bf16x4*)&Po[(size_t)prow * 64 + 8 * g + 4 * hi] = w4;
#pragma unroll
        for (int j = 0; j < 4; ++j) w4[j] = f2bf(o1[g * 4 + j] * inv);
        *(bf16x4*)&Po[(size_t)prow * 64 + 32 + 8 * g + 4 * hi] = w4;
    }
    if (hi == 0) Pm[prow] = m_run + __log2f(l_tot);
}

// ---------------------------------------------------------------------------
// attn_combine: merge <=2 partials per q-row -> fp32 Out [B,H,S,64] flat.
//   qt < 16 : single partial at u = 32+qt
//   qt >= 16: partials at u0 = qt-16 (tiles 0..15) and u1 = 47-qt (rest)
// ---------------------------------------------------------------------------
__global__ __launch_bounds__(256)
void attn_combine(const short* __restrict__ Po, const float* __restrict__ Pm,
                  float* __restrict__ Out) {
    const int idx = blockIdx.x * 256 + threadIdx.x;
    const int d4 = (idx & 15) << 2;
    const int rg = idx >> 4;
    const int q  = rg & 2047;
    const int bh = rg >> 11;
    const int qt = q >> 6, r = q & 63;

    f32x4 ov;
    if (qt < 16) {
        const int p0 = (bh * 48 + 32 + qt) * 64 + r;
        bf16x4 a = *(const bf16x4*)&Po[(size_t)p0 * 64 + d4];
#pragma unroll
        for (int j = 0; j < 4; ++j) ov[j] = bf2f(a[j]);
    } else {
        const int p0 = (bh * 48 + (qt - 16)) * 64 + r;
        const int p1 = (bh * 48 + (47 - qt)) * 64 + r;
        bf16x4 a = *(const bf16x4*)&Po[(size_t)p0 * 64 + d4];
        bf16x4 c = *(const bf16x4*)&Po[(size_t)p1 * 64 + d4];
        const float m0 = Pm[p0], m1 = Pm[p1];
        const float M = fmaxf(m0, m1);
        const float w0 = exp2f(m0 - M), w1 = exp2f(m1 - M);
        const float inv = 1.f / (w0 + w1);
#pragma unroll
        for (int j = 0; j < 4; ++j) ov[j] = (w0 * bf2f(a[j]) + w1 * bf2f(c[j])) * inv;
    }
    *(f32x4*)&Out[(size_t)rg * 64 + d4] = ov;
}

extern "C" void kernel_launch(void* const* d_in, const int* in_sizes, int n_in,
                              void* d_out, int out_size, void* d_ws, size_t ws_size,
                              hipStream_t stream) {
    const float* x  = (const float*)d_in[0];
    const float* W0 = (const float*)d_in[1];
    const float* b0 = (const float*)d_in[2];
    float* out = (float*)d_out;
    char* ws = (char*)d_ws;

    const size_t QKV_B = (size_t)4096 * 3072 * 2;     // 25.17 MB
    const size_t XBF_B = (size_t)4096 * 1024 * 2;     // 8.39 MB
    const size_t PO_B  = (size_t)1536 * 64 * 64 * 2;  // 12.58 MB

    short* qkv = (short*)ws;
    short* xb  = (short*)(ws + QKV_B);
    short* wt  = (short*)(ws + QKV_B + XBF_B);
    short* po  = (short*)(ws + QKV_B);                // reuse xb/wt after gemm
    float* pm  = (float*)(ws + QKV_B + PO_B);

    convert_x<<<dim3(2048), dim3(256), 0, stream>>>(x, xb);
    convert_wt<<<dim3(48, 16), dim3(256), 0, stream>>>(W0, wt);
    gemm_bf16<<<dim3(768), dim3(256), 0, stream>>>(xb, wt, b0, qkv);
    attn_part<<<dim3(48, 32), dim3(128), 0, stream>>>(qkv, po, pm);
    attn_combine<<<dim3(4096), dim3(256), 0, stream>>>(po, pm, out);
}